// Round 7
// baseline (10660.726 us; speedup 1.0000x reference)
//
#include <hip/hip_runtime.h>

#define NB 256   // batch
#define HH 128   // hidden
#define GG 512   // 4*H gate rows

typedef __attribute__((ext_vector_type(8))) short bf8;   // 8 bf16 (4 VGPRs)
typedef __attribute__((ext_vector_type(4))) float f32x4; // MFMA C/D

// ---------------------------------------------------------------------------
// fp32 GEMM over (b, ti) rows (unchanged):
//   C[b, tC0+ti, n] = sum_k A[b, t00+ti+tsh, k] * W[n, k] + b1[n] (+ b2[n])
// ---------------------------------------------------------------------------
#define BM 128
#define BN 128
#define KS 16
#define LPITCH 132

__global__ __launch_bounds__(256, 2) void proj_gemm(
    const float* __restrict__ A, long long lda_b, long long lda_t, int t00, int tsh,
    const float* __restrict__ W,
    const float* __restrict__ b1, const float* __restrict__ b2,
    float* __restrict__ C, long long ldc_b, long long ldc_t, int tC0,
    int CH, int K, int N)
{
  __shared__ float As[KS * LPITCH];
  __shared__ float Ws[KS * LPITCH];

  const int tid = threadIdx.x;
  const int tx = tid & 15;
  const int ty = tid >> 4;

  const long long row0 = (long long)blockIdx.x * BM;
  const int nbase = blockIdx.y * BN;

  const int lr  = tid >> 1;
  const int lks = (tid & 1) * 8;
  const long long lrow = row0 + lr;
  const int lb  = (int)(lrow / CH);
  const int lti = (int)(lrow - (long long)lb * CH);
  const int lt  = t00 + lti + tsh;
  const float* Arow = (lt >= 0) ? (A + (long long)lb * lda_b + (long long)lt * lda_t)
                                : (const float*)nullptr;
  const int ln = nbase + lr;
  const float* Wrow = (ln < N) ? (W + (long long)ln * K) : (const float*)nullptr;

  float acc[8][8];
#pragma unroll
  for (int i = 0; i < 8; ++i)
#pragma unroll
    for (int j = 0; j < 8; ++j) acc[i][j] = 0.f;

  const int nS = (K + KS - 1) / KS;

  float4 ra0 = make_float4(0.f,0.f,0.f,0.f), ra1 = ra0, rw0 = ra0, rw1 = ra0;

  auto loadRegs = [&](int s) {
    const int k0 = s * KS + lks;
    const float4 z = make_float4(0.f, 0.f, 0.f, 0.f);
    ra0 = (Arow && (k0 + 4 <= K)) ? *(const float4*)(Arow + k0)     : z;
    ra1 = (Arow && (k0 + 8 <= K)) ? *(const float4*)(Arow + k0 + 4) : z;
    rw0 = (Wrow && (k0 + 4 <= K)) ? *(const float4*)(Wrow + k0)     : z;
    rw1 = (Wrow && (k0 + 8 <= K)) ? *(const float4*)(Wrow + k0 + 4) : z;
  };

  loadRegs(0);

  for (int s = 0; s < nS; ++s) {
    __syncthreads();
    {
      float av[8] = {ra0.x, ra0.y, ra0.z, ra0.w, ra1.x, ra1.y, ra1.z, ra1.w};
      float wv[8] = {rw0.x, rw0.y, rw0.z, rw0.w, rw1.x, rw1.y, rw1.z, rw1.w};
#pragma unroll
      for (int j = 0; j < 8; ++j) {
        As[(lks + j) * LPITCH + lr] = av[j];
        Ws[(lks + j) * LPITCH + lr] = wv[j];
      }
    }
    __syncthreads();
    if (s + 1 < nS) loadRegs(s + 1);

#pragma unroll
    for (int kk = 0; kk < KS; ++kk) {
      const float* ar = &As[kk * LPITCH];
      const float* wr = &Ws[kk * LPITCH];
      float4 A0 = *(const float4*)(ar + ty * 8);
      float4 A1 = *(const float4*)(ar + ty * 8 + 4);
      float4 W0 = *(const float4*)(wr + tx * 4);
      float4 W1 = *(const float4*)(wr + 64 + tx * 4);
      float am[8] = {A0.x, A0.y, A0.z, A0.w, A1.x, A1.y, A1.z, A1.w};
      float wm[8] = {W0.x, W0.y, W0.z, W0.w, W1.x, W1.y, W1.z, W1.w};
#pragma unroll
      for (int i = 0; i < 8; ++i)
#pragma unroll
        for (int j = 0; j < 8; ++j)
          acc[i][j] = fmaf(am[i], wm[j], acc[i][j]);
    }
  }

  const bool fullN = (nbase + BN <= N);
#pragma unroll
  for (int i = 0; i < 8; ++i) {
    long long row = row0 + ty * 8 + i;
    int bb = (int)(row / CH);
    int ti = (int)(row - (long long)bb * CH);
    float* crow = C + (long long)bb * ldc_b + (long long)(tC0 + ti) * ldc_t;
    if (fullN) {
      int c0 = nbase + tx * 4;
      int c1 = nbase + 64 + tx * 4;
      const float4 bv0 = *(const float4*)(b1 + c0);
      const float4 bv1 = *(const float4*)(b1 + c1);
      float4 v0 = make_float4(acc[i][0] + bv0.x, acc[i][1] + bv0.y,
                              acc[i][2] + bv0.z, acc[i][3] + bv0.w);
      float4 v1 = make_float4(acc[i][4] + bv1.x, acc[i][5] + bv1.y,
                              acc[i][6] + bv1.z, acc[i][7] + bv1.w);
      if (b2) {
        const float4 c20 = *(const float4*)(b2 + c0);
        const float4 c21 = *(const float4*)(b2 + c1);
        v0.x += c20.x; v0.y += c20.y; v0.z += c20.z; v0.w += c20.w;
        v1.x += c21.x; v1.y += c21.y; v1.z += c21.z; v1.w += c21.w;
      }
      *(float4*)(crow + c0) = v0;
      *(float4*)(crow + c1) = v1;
    } else {
#pragma unroll
      for (int j = 0; j < 8; ++j) {
        int col = nbase + ((j < 4) ? (tx * 4 + j) : (64 + tx * 4 + (j - 4)));
        if (col < N) {
          float bv = b1[col];
          if (b2) bv += b2[col];
          crow[col] = acc[i][j] + bv;
        }
      }
    }
  }
}

// ---------------------------------------------------------------------------
// bf16 split helpers + weight prep kernel (fp32 -> hi/lo bf16, RNE)
// ---------------------------------------------------------------------------
__device__ __forceinline__ unsigned short f2bf(float f) {
  unsigned int u = __float_as_uint(f);
  return (unsigned short)((u + 0x7fffu + ((u >> 16) & 1u)) >> 16);
}
__device__ __forceinline__ float bf2f(unsigned short h) {
  return __uint_as_float(((unsigned int)h) << 16);
}

__global__ void split_bf16(const float* __restrict__ src,
                           unsigned short* __restrict__ hi,
                           unsigned short* __restrict__ lo, int n)
{
  int i = blockIdx.x * blockDim.x + threadIdx.x;
  if (i < n) {
    float v = src[i];
    unsigned short h = f2bf(v);
    hi[i] = h;
    lo[i] = f2bf(v - bf2f(h));
  }
}

__device__ __forceinline__ void barrier_lgkm() {
  asm volatile("s_waitcnt lgkmcnt(0)\n\ts_barrier" ::: "memory");
}
__device__ __forceinline__ float sigm_fast(float x) {
  float e = __expf(-x);
  return __builtin_amdgcn_rcpf(1.f + e);
}
__device__ __forceinline__ float tanh_fast(float x) {
  float e = __expf(2.f * x);
  return fmaf(-2.f, __builtin_amdgcn_rcpf(e + 1.f), 1.f);
}

// ---------------------------------------------------------------------------
// MFMA LSTM recurrence. 16 blocks x 256 threads (4 waves, 1 wave/SIMD).
// Round-6 counters: Occupancy 0.76% (16 blocks = 16/256 CUs -> structural,
// N=16 per MFMA and 512-gate feedback pin batch/block at 16); per-active-CU
// MfmaUtil ~35%, step 4350 cyc -> dependency-stall-bound: old emission order
// gave each acc[m] 12 CONSECUTIVE dependent MFMAs. This round: term-major /
// kt / m ordering -> every run of 8 consecutive MFMAs hits 8 different accs
// (8-way ILP, dependent reuse 8 instrs apart).
// D[gate][batch] = Whh @ h; A = weights (bf16 hi/lo, register/AGPR-stationary,
// MFMA reads AGPR natively), B = h in LDS [batch][k] pitch 136 (dbuf).
// 3-term split-bf16: Whi@hhi + Wlo@hhi + Whi@hlo (~2^-18 rel).
// Wave w owns gate rows T*128 + w*32 + s*16 + bl -> i,f,g,o of each h elem
// land in the SAME lane => lane-local cell update; one lgkm barrier/step.
// C/D layout (m89): row=(l>>4)*4+reg, col=l&15.
// A/B layout (m162): elems 0-3: k=4*(l>>4)+j; elems 4-7: +16.
// ---------------------------------------------------------------------------
#define HP 136

__global__ __launch_bounds__(256, 1) void lstm_rec_mfma(
    const float* __restrict__ xp,        // [NB][CH][GG] x-proj (+biases)
    const unsigned short* __restrict__ whi,  // [GG][HH] bf16 hi
    const unsigned short* __restrict__ wlo,  // [GG][HH] bf16 lo
    float* __restrict__ h_state,         // [NB][HH]
    float* __restrict__ c_state,         // [NB][HH]
    float* __restrict__ out_seq,         // [NB][CH][HH] or nullptr
    int CH, int init)
{
  __shared__ unsigned short hbuf[2][2][16][HP];   // [buf][hi/lo][batch][k]

  const int tid  = threadIdx.x;
  const int lane = tid & 63;
  const int w    = tid >> 6;        // wave 0..3
  const int g4   = lane >> 4;       // lane group 0..3
  const int bl   = lane & 15;       // batch-in-block / gate-row-in-tile
  const int bb   = blockIdx.x * 16 + bl;   // global batch
  const int hwb  = w * 32 + 4 * g4;        // this lane's hidx base (s=0)

  // ---- weight fragments (one-time global loads) ----
  bf8 WH[8][4], WL[8][4];
#pragma unroll
  for (int m = 0; m < 8; ++m) {
    const int T = m >> 1, s = m & 1;
    const int grow = T * 128 + w * 32 + s * 16 + bl;
    const unsigned short* rh = whi + grow * 128 + 4 * g4;
    const unsigned short* rl = wlo + grow * 128 + 4 * g4;
#pragma unroll
    for (int kt = 0; kt < 4; ++kt) {
      ushort4 a0 = *(const ushort4*)(rh + 32 * kt);
      ushort4 a1 = *(const ushort4*)(rh + 32 * kt + 16);
      WH[m][kt] = (bf8){(short)a0.x,(short)a0.y,(short)a0.z,(short)a0.w,
                        (short)a1.x,(short)a1.y,(short)a1.z,(short)a1.w};
      ushort4 b0 = *(const ushort4*)(rl + 32 * kt);
      ushort4 b1 = *(const ushort4*)(rl + 32 * kt + 16);
      WL[m][kt] = (bf8){(short)b0.x,(short)b0.y,(short)b0.z,(short)b0.w,
                        (short)b1.x,(short)b1.y,(short)b1.z,(short)b1.w};
    }
  }

  // ---- initial state (lane owns batch bb, hidx {hwb..+3, hwb+16..+19}) ----
  float cst[8], hs[8];
  if (init) {
#pragma unroll
    for (int i = 0; i < 8; ++i) { cst[i] = 0.f; hs[i] = 0.f; }
  } else {
#pragma unroll
    for (int s = 0; s < 2; ++s) {
      float4 cv = *(const float4*)&c_state[bb * HH + hwb + s * 16];
      float4 hv = *(const float4*)&h_state[bb * HH + hwb + s * 16];
      cst[s*4+0]=cv.x; cst[s*4+1]=cv.y; cst[s*4+2]=cv.z; cst[s*4+3]=cv.w;
      hs [s*4+0]=hv.x; hs [s*4+1]=hv.y; hs [s*4+2]=hv.z; hs [s*4+3]=hv.w;
    }
  }
  // publish initial h into buf0 (hi/lo planes)
#pragma unroll
  for (int s = 0; s < 2; ++s) {
    unsigned short h0=f2bf(hs[s*4+0]), h1=f2bf(hs[s*4+1]),
                   h2=f2bf(hs[s*4+2]), h3=f2bf(hs[s*4+3]);
    ushort4 hi4 = (ushort4){h0,h1,h2,h3};
    ushort4 lo4 = (ushort4){f2bf(hs[s*4+0]-bf2f(h0)), f2bf(hs[s*4+1]-bf2f(h1)),
                            f2bf(hs[s*4+2]-bf2f(h2)), f2bf(hs[s*4+3]-bf2f(h3))};
    *(ushort4*)&hbuf[0][0][bl][hwb + s * 16] = hi4;
    *(ushort4*)&hbuf[0][1][bl][hwb + s * 16] = lo4;
  }
  barrier_lgkm();

  // ---- xp pointers + prefetch t=0 (8 float4 per lane; C-init values) ----
  const float* xpt = xp + (long long)bb * CH * GG + w * 32 + 4 * g4;
  f32x4 xpr[8];
#pragma unroll
  for (int m = 0; m < 8; ++m)
    xpr[m] = *(const f32x4*)(xpt + (m >> 1) * 128 + (m & 1) * 16);

  float* osq = out_seq ? (out_seq + (long long)bb * CH * HH + hwb) : (float*)nullptr;

  for (int t = 0; t < CH; ++t) {
    const int buf = t & 1;

    // ---- B fragments: h hi/lo for 4 K-tiles (ds_read_b64 pairs) ----
    bf8 BH[4], BL[4];
    const unsigned short* hbH = &hbuf[buf][0][bl][4 * g4];
    const unsigned short* hbL = &hbuf[buf][1][bl][4 * g4];
#pragma unroll
    for (int kt = 0; kt < 4; ++kt) {
      ushort4 a0 = *(const ushort4*)(hbH + 32 * kt);
      ushort4 a1 = *(const ushort4*)(hbH + 32 * kt + 16);
      BH[kt] = (bf8){(short)a0.x,(short)a0.y,(short)a0.z,(short)a0.w,
                     (short)a1.x,(short)a1.y,(short)a1.z,(short)a1.w};
      ushort4 b0 = *(const ushort4*)(hbL + 32 * kt);
      ushort4 b1 = *(const ushort4*)(hbL + 32 * kt + 16);
      BL[kt] = (bf8){(short)b0.x,(short)b0.y,(short)b0.z,(short)b0.w,
                     (short)b1.x,(short)b1.y,(short)b1.z,(short)b1.w};
    }

    // ---- accumulators init = xp; then prefetch next step's xp ----
    f32x4 acc[8];
#pragma unroll
    for (int m = 0; m < 8; ++m) acc[m] = xpr[m];
    if (t + 1 < CH) {
      const float* xpn = xpt + 512;
#pragma unroll
      for (int m = 0; m < 8; ++m)
        xpr[m] = *(const f32x4*)(xpn + (m >> 1) * 128 + (m & 1) * 16);
    }

    // ---- MFMAs, term-major: consecutive runs of 8 independent accs ----
#pragma unroll
    for (int kt = 0; kt < 4; ++kt)
#pragma unroll
      for (int m = 0; m < 8; ++m)
        acc[m] = __builtin_amdgcn_mfma_f32_16x16x32_bf16(WH[m][kt], BH[kt], acc[m], 0, 0, 0);
#pragma unroll
    for (int kt = 0; kt < 4; ++kt)
#pragma unroll
      for (int m = 0; m < 8; ++m)
        acc[m] = __builtin_amdgcn_mfma_f32_16x16x32_bf16(WL[m][kt], BH[kt], acc[m], 0, 0, 0);
#pragma unroll
    for (int kt = 0; kt < 4; ++kt)
#pragma unroll
      for (int m = 0; m < 8; ++m)
        acc[m] = __builtin_amdgcn_mfma_f32_16x16x32_bf16(WH[m][kt], BL[kt], acc[m], 0, 0, 0);

    // ---- activations + cell update (lane-local: i,f,g,o same lane) ----
#pragma unroll
    for (int s = 0; s < 2; ++s) {
#pragma unroll
      for (int r = 0; r < 4; ++r) {
        float iv = sigm_fast(acc[0 + s][r]);
        float fv = sigm_fast(acc[2 + s][r]);
        float gv = tanh_fast(acc[4 + s][r]);
        float ov = sigm_fast(acc[6 + s][r]);
        float c  = fmaf(fv, cst[s * 4 + r], iv * gv);
        cst[s * 4 + r] = c;
        hs[s * 4 + r]  = ov * tanh_fast(c);
      }
      if (osq) {
        f32x4 h4 = {hs[s*4+0], hs[s*4+1], hs[s*4+2], hs[s*4+3]};
        *(f32x4*)(osq + (long long)t * HH + s * 16) = h4;
      }
      unsigned short h0=f2bf(hs[s*4+0]), h1=f2bf(hs[s*4+1]),
                     h2=f2bf(hs[s*4+2]), h3=f2bf(hs[s*4+3]);
      ushort4 hi4 = (ushort4){h0,h1,h2,h3};
      ushort4 lo4 = (ushort4){f2bf(hs[s*4+0]-bf2f(h0)), f2bf(hs[s*4+1]-bf2f(h1)),
                              f2bf(hs[s*4+2]-bf2f(h2)), f2bf(hs[s*4+3]-bf2f(h3))};
      *(ushort4*)&hbuf[buf ^ 1][0][bl][hwb + s * 16] = hi4;
      *(ushort4*)&hbuf[buf ^ 1][1][bl][hwb + s * 16] = lo4;
    }

    xpt += 512;
    barrier_lgkm();   // writes visible; prev reads drained; vmcnt untouched
  }

  // ---- store final state ----
#pragma unroll
  for (int s = 0; s < 2; ++s) {
    f32x4 c4 = {cst[s*4+0], cst[s*4+1], cst[s*4+2], cst[s*4+3]};
    f32x4 h4 = {hs[s*4+0], hs[s*4+1], hs[s*4+2], hs[s*4+3]};
    *(f32x4*)&c_state[bb * HH + hwb + s * 16] = c4;
    *(f32x4*)&h_state[bb * HH + hwb + s * 16] = h4;
  }
}

// ---------------------------------------------------------------------------
extern "C" void kernel_launch(void* const* d_in, const int* in_sizes, int n_in,
                              void* d_out, int out_size, void* d_ws, size_t ws_size,
                              hipStream_t stream)
{
  (void)in_sizes; (void)n_in; (void)out_size;

  const float* x     = (const float*)d_in[0];
  const float* y     = (const float*)d_in[1];
  const float* eWih0 = (const float*)d_in[2];
  const float* eWhh0 = (const float*)d_in[3];
  const float* ebih0 = (const float*)d_in[4];
  const float* ebhh0 = (const float*)d_in[5];
  const float* eWih1 = (const float*)d_in[6];
  const float* eWhh1 = (const float*)d_in[7];
  const float* ebih1 = (const float*)d_in[8];
  const float* ebhh1 = (const float*)d_in[9];
  const float* dWih0 = (const float*)d_in[10];
  const float* dWhh0 = (const float*)d_in[11];
  const float* dbih0 = (const float*)d_in[12];
  const float* dbhh0 = (const float*)d_in[13];
  const float* dWih1 = (const float*)d_in[14];
  const float* dWhh1 = (const float*)d_in[15];
  const float* dbih1 = (const float*)d_in[16];
  const float* dbhh1 = (const float*)d_in[17];
  const float* fcW   = (const float*)d_in[18];
  const float* fcb   = (const float*)d_in[19];
  float* out = (float*)d_out;

  const int S = 1024;
  const long long WN = (long long)GG * HH;            // 65536 per matrix
  const long long WSPLIT_BYTES = 4 * 2 * WN * 2;      // 1 MB

  // largest CH (<=256 for L3 residency) that fits ws
  int CH = 16;
  {
    const int cands[5] = {256, 128, 64, 32, 16};
    for (int i = 0; i < 5; ++i) {
      long long need = (long long)NB * cands[i] * 4LL * (GG + HH + HH)
                     + 4LL * NB * HH * 4
                     + WSPLIT_BYTES + 4096;
      if (need <= (long long)ws_size) { CH = cands[i]; break; }
    }
  }
  const int nchunks = S / CH;

  float* xpb  = (float*)d_ws;                          // [NB, CH, GG]
  float* seqA = xpb  + (long long)NB * CH * GG;        // [NB, CH, HH]
  float* seqB = seqA + (long long)NB * CH * HH;        // [NB, CH, HH]
  float* h0s  = seqB + (long long)NB * CH * HH;        // [NB, HH]
  float* c0s  = h0s + NB * HH;
  float* h1s  = c0s + NB * HH;
  float* c1s  = h1s + NB * HH;
  unsigned short* wsp = (unsigned short*)(c1s + NB * HH);
  unsigned short* eW0hi = wsp;             unsigned short* eW0lo = wsp + WN;
  unsigned short* eW1hi = wsp + 2 * WN;    unsigned short* eW1lo = wsp + 3 * WN;
  unsigned short* dW0hi = wsp + 4 * WN;    unsigned short* dW0lo = wsp + 5 * WN;
  unsigned short* dW1hi = wsp + 6 * WN;    unsigned short* dW1lo = wsp + 7 * WN;

  // weight prep: fp32 -> bf16 hi/lo
  {
    dim3 pg((WN + 255) / 256), pb(256);
    split_bf16<<<pg, pb, 0, stream>>>(eWhh0, eW0hi, eW0lo, (int)WN);
    split_bf16<<<pg, pb, 0, stream>>>(eWhh1, eW1hi, eW1lo, (int)WN);
    split_bf16<<<pg, pb, 0, stream>>>(dWhh0, dW0hi, dW0lo, (int)WN);
    split_bf16<<<pg, pb, 0, stream>>>(dWhh1, dW1hi, dW1lo, (int)WN);
  }

  dim3 pgrid((NB * CH) / BM, GG / BN);
  dim3 fgrid((NB * CH) / BM, (200 + BN - 1) / BN);
  dim3 pblk(256);
  dim3 rgrid(NB / 16);
  dim3 rblk(256);

  // ---------------- encoder ----------------
  for (int cidx = 0; cidx < nchunks; ++cidx) {
    int t0 = cidx * CH;
    proj_gemm<<<pgrid, pblk, 0, stream>>>(
        x, (long long)S * 100, 100, t0, 0,
        eWih0, ebih0, ebhh0,
        xpb, (long long)CH * GG, GG, 0, CH, 100, GG);
    lstm_rec_mfma<<<rgrid, rblk, 0, stream>>>(xpb, eW0hi, eW0lo, h0s, c0s, seqA, CH, cidx == 0 ? 1 : 0);
    proj_gemm<<<pgrid, pblk, 0, stream>>>(
        seqA, (long long)CH * HH, HH, 0, 0,
        eWih1, ebih1, ebhh1,
        xpb, (long long)CH * GG, GG, 0, CH, HH, GG);
    lstm_rec_mfma<<<rgrid, rblk, 0, stream>>>(xpb, eW1hi, eW1lo, h1s, c1s, (float*)nullptr, CH, cidx == 0 ? 1 : 0);
  }

  // ---------------- decoder (teacher-forced) + FC ----------------
  for (int cidx = 0; cidx < nchunks; ++cidx) {
    int t0 = cidx * CH;
    proj_gemm<<<pgrid, pblk, 0, stream>>>(
        y, (long long)S * 200, 200, t0, -1,
        dWih0, dbih0, dbhh0,
        xpb, (long long)CH * GG, GG, 0, CH, 200, GG);
    lstm_rec_mfma<<<rgrid, rblk, 0, stream>>>(xpb, dW0hi, dW0lo, h0s, c0s, seqA, CH, 0);
    proj_gemm<<<pgrid, pblk, 0, stream>>>(
        seqA, (long long)CH * HH, HH, 0, 0,
        dWih1, dbih1, dbhh1,
        xpb, (long long)CH * GG, GG, 0, CH, HH, GG);
    lstm_rec_mfma<<<rgrid, rblk, 0, stream>>>(xpb, dW1hi, dW1lo, h1s, c1s, seqB, CH, 0);
    proj_gemm<<<fgrid, pblk, 0, stream>>>(
        seqB, (long long)CH * HH, HH, 0, 0,
        fcW, fcb, (const float*)nullptr,
        out, (long long)S * 200, 200, t0, CH, HH, 200);
  }
}

// Round 10
// 7463.638 us; speedup vs baseline: 1.4284x; 1.4284x over previous
//
#include <hip/hip_runtime.h>

#define NB 256   // batch
#define HH 128   // hidden
#define GG 512   // 4*H gate rows

typedef __attribute__((ext_vector_type(8))) short bf8;   // 8 bf16 (4 VGPRs)
typedef __attribute__((ext_vector_type(4))) float f32x4; // MFMA C/D

// ---------------------------------------------------------------------------
// fp32 GEMM over (b, ti) rows (unchanged):
//   C[b, tC0+ti, n] = sum_k A[b, t00+ti+tsh, k] * W[n, k] + b1[n] (+ b2[n])
// ---------------------------------------------------------------------------
#define BM 128
#define BN 128
#define KS 16
#define LPITCH 132

__global__ __launch_bounds__(256, 2) void proj_gemm(
    const float* __restrict__ A, long long lda_b, long long lda_t, int t00, int tsh,
    const float* __restrict__ W,
    const float* __restrict__ b1, const float* __restrict__ b2,
    float* __restrict__ C, long long ldc_b, long long ldc_t, int tC0,
    int CH, int K, int N)
{
  __shared__ float As[KS * LPITCH];
  __shared__ float Ws[KS * LPITCH];

  const int tid = threadIdx.x;
  const int tx = tid & 15;
  const int ty = tid >> 4;

  const long long row0 = (long long)blockIdx.x * BM;
  const int nbase = blockIdx.y * BN;

  const int lr  = tid >> 1;
  const int lks = (tid & 1) * 8;
  const long long lrow = row0 + lr;
  const int lb  = (int)(lrow / CH);
  const int lti = (int)(lrow - (long long)lb * CH);
  const int lt  = t00 + lti + tsh;
  const float* Arow = (lt >= 0) ? (A + (long long)lb * lda_b + (long long)lt * lda_t)
                                : (const float*)nullptr;
  const int ln = nbase + lr;
  const float* Wrow = (ln < N) ? (W + (long long)ln * K) : (const float*)nullptr;

  float acc[8][8];
#pragma unroll
  for (int i = 0; i < 8; ++i)
#pragma unroll
    for (int j = 0; j < 8; ++j) acc[i][j] = 0.f;

  const int nS = (K + KS - 1) / KS;

  float4 ra0 = make_float4(0.f,0.f,0.f,0.f), ra1 = ra0, rw0 = ra0, rw1 = ra0;

  auto loadRegs = [&](int s) {
    const int k0 = s * KS + lks;
    const float4 z = make_float4(0.f, 0.f, 0.f, 0.f);
    ra0 = (Arow && (k0 + 4 <= K)) ? *(const float4*)(Arow + k0)     : z;
    ra1 = (Arow && (k0 + 8 <= K)) ? *(const float4*)(Arow + k0 + 4) : z;
    rw0 = (Wrow && (k0 + 4 <= K)) ? *(const float4*)(Wrow + k0)     : z;
    rw1 = (Wrow && (k0 + 8 <= K)) ? *(const float4*)(Wrow + k0 + 4) : z;
  };

  loadRegs(0);

  for (int s = 0; s < nS; ++s) {
    __syncthreads();
    {
      float av[8] = {ra0.x, ra0.y, ra0.z, ra0.w, ra1.x, ra1.y, ra1.z, ra1.w};
      float wv[8] = {rw0.x, rw0.y, rw0.z, rw0.w, rw1.x, rw1.y, rw1.z, rw1.w};
#pragma unroll
      for (int j = 0; j < 8; ++j) {
        As[(lks + j) * LPITCH + lr] = av[j];
        Ws[(lks + j) * LPITCH + lr] = wv[j];
      }
    }
    __syncthreads();
    if (s + 1 < nS) loadRegs(s + 1);

#pragma unroll
    for (int kk = 0; kk < KS; ++kk) {
      const float* ar = &As[kk * LPITCH];
      const float* wr = &Ws[kk * LPITCH];
      float4 A0 = *(const float4*)(ar + ty * 8);
      float4 A1 = *(const float4*)(ar + ty * 8 + 4);
      float4 W0 = *(const float4*)(wr + tx * 4);
      float4 W1 = *(const float4*)(wr + 64 + tx * 4);
      float am[8] = {A0.x, A0.y, A0.z, A0.w, A1.x, A1.y, A1.z, A1.w};
      float wm[8] = {W0.x, W0.y, W0.z, W0.w, W1.x, W1.y, W1.z, W1.w};
#pragma unroll
      for (int i = 0; i < 8; ++i)
#pragma unroll
        for (int j = 0; j < 8; ++j)
          acc[i][j] = fmaf(am[i], wm[j], acc[i][j]);
    }
  }

  const bool fullN = (nbase + BN <= N);
#pragma unroll
  for (int i = 0; i < 8; ++i) {
    long long row = row0 + ty * 8 + i;
    int bb = (int)(row / CH);
    int ti = (int)(row - (long long)bb * CH);
    float* crow = C + (long long)bb * ldc_b + (long long)(tC0 + ti) * ldc_t;
    if (fullN) {
      int c0 = nbase + tx * 4;
      int c1 = nbase + 64 + tx * 4;
      const float4 bv0 = *(const float4*)(b1 + c0);
      const float4 bv1 = *(const float4*)(b1 + c1);
      float4 v0 = make_float4(acc[i][0] + bv0.x, acc[i][1] + bv0.y,
                              acc[i][2] + bv0.z, acc[i][3] + bv0.w);
      float4 v1 = make_float4(acc[i][4] + bv1.x, acc[i][5] + bv1.y,
                              acc[i][6] + bv1.z, acc[i][7] + bv1.w);
      if (b2) {
        const float4 c20 = *(const float4*)(b2 + c0);
        const float4 c21 = *(const float4*)(b2 + c1);
        v0.x += c20.x; v0.y += c20.y; v0.z += c20.z; v0.w += c20.w;
        v1.x += c21.x; v1.y += c21.y; v1.z += c21.z; v1.w += c21.w;
      }
      *(float4*)(crow + c0) = v0;
      *(float4*)(crow + c1) = v1;
    } else {
#pragma unroll
      for (int j = 0; j < 8; ++j) {
        int col = nbase + ((j < 4) ? (tx * 4 + j) : (64 + tx * 4 + (j - 4)));
        if (col < N) {
          float bv = b1[col];
          if (b2) bv += b2[col];
          crow[col] = acc[i][j] + bv;
        }
      }
    }
  }
}

// ---------------------------------------------------------------------------
// bf16 split helpers + weight prep kernel (fp32 -> hi/lo bf16, RNE)
// ---------------------------------------------------------------------------
__device__ __forceinline__ unsigned short f2bf(float f) {
  unsigned int u = __float_as_uint(f);
  return (unsigned short)((u + 0x7fffu + ((u >> 16) & 1u)) >> 16);
}
__device__ __forceinline__ float bf2f(unsigned short h) {
  return __uint_as_float(((unsigned int)h) << 16);
}

__global__ void split_bf16(const float* __restrict__ src,
                           unsigned short* __restrict__ hi,
                           unsigned short* __restrict__ lo, int n)
{
  int i = blockIdx.x * blockDim.x + threadIdx.x;
  if (i < n) {
    float v = src[i];
    unsigned short h = f2bf(v);
    hi[i] = h;
    lo[i] = f2bf(v - bf2f(h));
  }
}

__device__ __forceinline__ void barrier_lgkm() {
  asm volatile("s_waitcnt lgkmcnt(0)\n\ts_barrier" ::: "memory");
}
__device__ __forceinline__ float sigm_fast(float x) {
  float e = __expf(-x);
  return __builtin_amdgcn_rcpf(1.f + e);
}
__device__ __forceinline__ float tanh_fast(float x) {
  float e = __expf(2.f * x);
  return fmaf(-2.f, __builtin_amdgcn_rcpf(e + 1.f), 1.f);
}

// pack 8 bf16 (two 8B groups, 32B apart) into one bf8 with zero VALU
union BF8U { uint4 u; bf8 v; };
__device__ __forceinline__ bf8 mk_bf8(const unsigned short* p) {
  uint2 a = *(const uint2*)(p);        // k-elems j=0..3
  uint2 b = *(const uint2*)(p + 16);   // k-elems j=4..7 (k+16)
  BF8U t; t.u = make_uint4(a.x, a.y, b.x, b.y);
  return t.v;
}

// ---------------------------------------------------------------------------
// Dual-job MFMA LSTM recurrence. Grid = 32 blocks x 512 threads (8 waves,
// 2 waves/SIMD). Blocks 0-15 run job A, 16-31 job B (two independent
// layer-chunk recurrences, pipelined by the host: L0 chunk j || L1 chunk j-1).
// Round-7 lesson: 1 wave/SIMD serial chain (ds_read->MFMA->act->publish) had
// no TLP; VALUBusy/CU 45%. 8 waves: wave (wq=w>>1, s=w&1) owns 4 M-tiles
// (T=i,f,g,o at hidx half s, quarter wq) -> per-wave chain halves, 2
// waves/SIMD interleave. uint4-bitcast fragment packing (no per-short casts).
// D[gate][batch] = Whh @ h; A = weights bf16 hi/lo (register/AGPR-stationary),
// B = h in LDS [batch][k] pitch 136 (double-buffered).
// 3-term split-bf16: Whi@hhi + Wlo@hhi + Whi@hlo.
// C/D layout (m89): row=(l>>4)*4+reg, col=l&15  => lane owns batch bl,
// hidx wq*32+s*16+4*g4+r with i,f,g,o in acc[0..3][r] -> lane-local update.
// A/B layout (m162): elems 0-3: k=4*(l>>4)+j; elems 4-7: +16.
// One lgkm-only barrier per step (xp prefetch stays in flight).
// ---------------------------------------------------------------------------
#define HP 136

__global__ __launch_bounds__(512, 2) void lstm_rec_mfma2(
    const float* __restrict__ xpA, const unsigned short* __restrict__ whiA,
    const unsigned short* __restrict__ wloA,
    float* __restrict__ hA, float* __restrict__ cA, float* __restrict__ oA, int initA,
    const float* __restrict__ xpB, const unsigned short* __restrict__ whiB,
    const unsigned short* __restrict__ wloB,
    float* __restrict__ hB, float* __restrict__ cB, float* __restrict__ oB, int initB,
    int CH)
{
  const int job = blockIdx.x >> 4;
  const int jb  = blockIdx.x & 15;

  const float* xp = job ? xpB : xpA;
  if (!xp) return;
  const unsigned short* whi = job ? whiB : whiA;
  const unsigned short* wlo = job ? wloB : wloA;
  float* h_state = job ? hB : hA;
  float* c_state = job ? cB : cA;
  float* out_seq = job ? oB : oA;
  const int init = job ? initB : initA;

  __shared__ unsigned short hbuf[2][2][16][HP];   // [buf][hi/lo][batch][k]

  const int tid  = threadIdx.x;
  const int lane = tid & 63;
  const int wv   = tid >> 6;        // wave 0..7
  const int wq   = wv >> 1;         // hidx quarter 0..3
  const int s    = wv & 1;          // hidx half-of-quarter
  const int g4   = lane >> 4;       // lane group 0..3
  const int bl   = lane & 15;       // batch-in-block
  const int bb   = jb * 16 + bl;    // global batch
  const int hwb  = wq * 32 + s * 16 + 4 * g4;   // lane's hidx base (4 elems)

  // ---- weight fragments: 4 M-tiles (T=i,f,g,o) x 4 K-tiles, hi+lo ----
  bf8 WH[4][4], WL[4][4];
#pragma unroll
  for (int T = 0; T < 4; ++T) {
    const int grow = T * 128 + wq * 32 + s * 16 + bl;
    const unsigned short* rh = whi + grow * 128 + 4 * g4;
    const unsigned short* rl = wlo + grow * 128 + 4 * g4;
#pragma unroll
    for (int kt = 0; kt < 4; ++kt) {
      WH[T][kt] = mk_bf8(rh + 32 * kt);
      WL[T][kt] = mk_bf8(rl + 32 * kt);
    }
  }

  // ---- initial state: lane owns batch bb, hidx hwb..hwb+3 ----
  float cst[4], hs[4];
  if (init) {
#pragma unroll
    for (int i = 0; i < 4; ++i) { cst[i] = 0.f; hs[i] = 0.f; }
  } else {
    float4 cv = *(const float4*)&c_state[bb * HH + hwb];
    float4 hv = *(const float4*)&h_state[bb * HH + hwb];
    cst[0]=cv.x; cst[1]=cv.y; cst[2]=cv.z; cst[3]=cv.w;
    hs [0]=hv.x; hs [1]=hv.y; hs [2]=hv.z; hs [3]=hv.w;
  }
  {
    unsigned short h0=f2bf(hs[0]), h1=f2bf(hs[1]), h2=f2bf(hs[2]), h3=f2bf(hs[3]);
    ushort4 hi4 = make_ushort4(h0,h1,h2,h3);
    ushort4 lo4 = make_ushort4(f2bf(hs[0]-bf2f(h0)), f2bf(hs[1]-bf2f(h1)),
                               f2bf(hs[2]-bf2f(h2)), f2bf(hs[3]-bf2f(h3)));
    *(ushort4*)&hbuf[0][0][bl][hwb] = hi4;
    *(ushort4*)&hbuf[0][1][bl][hwb] = lo4;
  }
  barrier_lgkm();

  // ---- xp base + prefetch t=0 (4 f32x4 per lane = lane's C-init) ----
  const float* xpt = xp + (long long)bb * CH * GG + wq * 32 + s * 16 + 4 * g4;
  f32x4 xpr[4];
#pragma unroll
  for (int T = 0; T < 4; ++T)
    xpr[T] = *(const f32x4*)(xpt + T * 128);

  float* osq = out_seq ? (out_seq + (long long)bb * CH * HH + hwb) : (float*)nullptr;

  for (int t = 0; t < CH; ++t) {
    const int buf = t & 1;

    // ---- B fragments (h hi/lo, all 4 K-tiles; same for every wave) ----
    bf8 BH[4], BL[4];
    const unsigned short* hbH = &hbuf[buf][0][bl][4 * g4];
    const unsigned short* hbL = &hbuf[buf][1][bl][4 * g4];
#pragma unroll
    for (int kt = 0; kt < 4; ++kt) {
      BH[kt] = mk_bf8(hbH + 32 * kt);
      BL[kt] = mk_bf8(hbL + 32 * kt);
    }

    // ---- acc init = xp; prefetch next step's xp ----
    f32x4 acc[4];
#pragma unroll
    for (int T = 0; T < 4; ++T) acc[T] = xpr[T];
    if (t + 1 < CH) {
      const float* xpn = xpt + GG;
#pragma unroll
      for (int T = 0; T < 4; ++T)
        xpr[T] = *(const f32x4*)(xpn + T * 128);
    }

    // ---- 48 MFMAs: 3 split terms x 4 kt x 4 independent acc tiles ----
#pragma unroll
    for (int kt = 0; kt < 4; ++kt)
#pragma unroll
      for (int T = 0; T < 4; ++T)
        acc[T] = __builtin_amdgcn_mfma_f32_16x16x32_bf16(WH[T][kt], BH[kt], acc[T], 0, 0, 0);
#pragma unroll
    for (int kt = 0; kt < 4; ++kt)
#pragma unroll
      for (int T = 0; T < 4; ++T)
        acc[T] = __builtin_amdgcn_mfma_f32_16x16x32_bf16(WL[T][kt], BH[kt], acc[T], 0, 0, 0);
#pragma unroll
    for (int kt = 0; kt < 4; ++kt)
#pragma unroll
      for (int T = 0; T < 4; ++T)
        acc[T] = __builtin_amdgcn_mfma_f32_16x16x32_bf16(WH[T][kt], BL[kt], acc[T], 0, 0, 0);

    // ---- activations + cell update (i,f,g,o all in this lane) ----
#pragma unroll
    for (int r = 0; r < 4; ++r) {
      float iv = sigm_fast(acc[0][r]);
      float fv = sigm_fast(acc[1][r]);
      float gv = tanh_fast(acc[2][r]);
      float ov = sigm_fast(acc[3][r]);
      float c  = fmaf(fv, cst[r], iv * gv);
      cst[r] = c;
      hs[r]  = ov * tanh_fast(c);
    }
    if (osq) {
      f32x4 h4 = {hs[0], hs[1], hs[2], hs[3]};
      *(f32x4*)(osq + (long long)t * HH) = h4;
    }
    {
      unsigned short h0=f2bf(hs[0]), h1=f2bf(hs[1]), h2=f2bf(hs[2]), h3=f2bf(hs[3]);
      ushort4 hi4 = make_ushort4(h0,h1,h2,h3);
      ushort4 lo4 = make_ushort4(f2bf(hs[0]-bf2f(h0)), f2bf(hs[1]-bf2f(h1)),
                                 f2bf(hs[2]-bf2f(h2)), f2bf(hs[3]-bf2f(h3)));
      *(ushort4*)&hbuf[buf ^ 1][0][bl][hwb] = hi4;
      *(ushort4*)&hbuf[buf ^ 1][1][bl][hwb] = lo4;
    }

    xpt += GG;
    barrier_lgkm();   // publish visible; prev reads drained; vmcnt untouched
  }

  // ---- store final state ----
  {
    f32x4 c4 = {cst[0], cst[1], cst[2], cst[3]};
    f32x4 h4 = {hs[0], hs[1], hs[2], hs[3]};
    *(f32x4*)&c_state[bb * HH + hwb] = c4;
    *(f32x4*)&h_state[bb * HH + hwb] = h4;
  }
}

// ---------------------------------------------------------------------------
extern "C" void kernel_launch(void* const* d_in, const int* in_sizes, int n_in,
                              void* d_out, int out_size, void* d_ws, size_t ws_size,
                              hipStream_t stream)
{
  (void)in_sizes; (void)n_in; (void)out_size;

  const float* x     = (const float*)d_in[0];
  const float* y     = (const float*)d_in[1];
  const float* eWih0 = (const float*)d_in[2];
  const float* eWhh0 = (const float*)d_in[3];
  const float* ebih0 = (const float*)d_in[4];
  const float* ebhh0 = (const float*)d_in[5];
  const float* eWih1 = (const float*)d_in[6];
  const float* eWhh1 = (const float*)d_in[7];
  const float* ebih1 = (const float*)d_in[8];
  const float* ebhh1 = (const float*)d_in[9];
  const float* dWih0 = (const float*)d_in[10];
  const float* dWhh0 = (const float*)d_in[11];
  const float* dbih0 = (const float*)d_in[12];
  const float* dbhh0 = (const float*)d_in[13];
  const float* dWih1 = (const float*)d_in[14];
  const float* dWhh1 = (const float*)d_in[15];
  const float* dbih1 = (const float*)d_in[16];
  const float* dbhh1 = (const float*)d_in[17];
  const float* fcW   = (const float*)d_in[18];
  const float* fcb   = (const float*)d_in[19];
  float* out = (float*)d_out;

  const int S = 1024;
  const long long WN = (long long)GG * HH;            // 65536 per matrix
  const long long WSPLIT_BYTES = 4 * 2 * WN * 2;      // 1 MB

  // largest CH (<=256 for L3 residency) whose footprint fits ws.
  // Pipelined layout needs TWO xp buffers (jobs A and B run concurrently).
  int CH = 16;
  {
    const int cands[5] = {256, 128, 64, 32, 16};
    for (int i = 0; i < 5; ++i) {
      long long need = (long long)NB * cands[i] * 4LL * (2 * GG + HH + HH)
                     + 4LL * NB * HH * 4
                     + WSPLIT_BYTES + 4096;
      if (need <= (long long)ws_size) { CH = cands[i]; break; }
    }
  }
  const int nchunks = S / CH;

  float* xpA  = (float*)d_ws;                          // [NB, CH, GG]
  float* xpB  = xpA  + (long long)NB * CH * GG;        // [NB, CH, GG]
  float* seqA = xpB  + (long long)NB * CH * GG;        // [NB, CH, HH]
  float* seqB = seqA + (long long)NB * CH * HH;        // [NB, CH, HH]
  float* h0s  = seqB + (long long)NB * CH * HH;        // [NB, HH]
  float* c0s  = h0s + NB * HH;
  float* h1s  = c0s + NB * HH;
  float* c1s  = h1s + NB * HH;
  unsigned short* wsp = (unsigned short*)(c1s + NB * HH);
  unsigned short* eW0hi = wsp;             unsigned short* eW0lo = wsp + WN;
  unsigned short* eW1hi = wsp + 2 * WN;    unsigned short* eW1lo = wsp + 3 * WN;
  unsigned short* dW0hi = wsp + 4 * WN;    unsigned short* dW0lo = wsp + 5 * WN;
  unsigned short* dW1hi = wsp + 6 * WN;    unsigned short* dW1lo = wsp + 7 * WN;

  // weight prep: fp32 -> bf16 hi/lo
  {
    dim3 pg((WN + 255) / 256), pb(256);
    split_bf16<<<pg, pb, 0, stream>>>(eWhh0, eW0hi, eW0lo, (int)WN);
    split_bf16<<<pg, pb, 0, stream>>>(eWhh1, eW1hi, eW1lo, (int)WN);
    split_bf16<<<pg, pb, 0, stream>>>(dWhh0, dW0hi, dW0lo, (int)WN);
    split_bf16<<<pg, pb, 0, stream>>>(dWhh1, dW1hi, dW1lo, (int)WN);
  }

  dim3 pgrid((NB * CH) / BM, GG / BN);
  dim3 fgrid((NB * CH) / BM, (200 + BN - 1) / BN);
  dim3 pblk(256);
  dim3 rgrid(32);
  dim3 rblk(512);

  // ---------------- encoder: L0(chunk j) || L1(chunk j-1) ----------------
  for (int j = 0; j <= nchunks; ++j) {
    if (j < nchunks)
      proj_gemm<<<pgrid, pblk, 0, stream>>>(
          x, (long long)S * 100, 100, j * CH, 0,
          eWih0, ebih0, ebhh0,
          xpA, (long long)CH * GG, GG, 0, CH, 100, GG);
    if (j >= 1)
      proj_gemm<<<pgrid, pblk, 0, stream>>>(
          seqA, (long long)CH * HH, HH, 0, 0,
          eWih1, ebih1, ebhh1,
          xpB, (long long)CH * GG, GG, 0, CH, HH, GG);
    lstm_rec_mfma2<<<rgrid, rblk, 0, stream>>>(
        (j < nchunks) ? xpA : (const float*)nullptr, eW0hi, eW0lo,
        h0s, c0s, seqA, (j == 0) ? 1 : 0,
        (j >= 1) ? xpB : (const float*)nullptr, eW1hi, eW1lo,
        h1s, c1s, (float*)nullptr, (j == 1) ? 1 : 0,
        CH);
  }

  // -------- decoder (teacher-forced): dL0(j) || dL1(j-1), FC(j-1) --------
  for (int j = 0; j <= nchunks; ++j) {
    if (j < nchunks)
      proj_gemm<<<pgrid, pblk, 0, stream>>>(
          y, (long long)S * 200, 200, j * CH, -1,
          dWih0, dbih0, dbhh0,
          xpA, (long long)CH * GG, GG, 0, CH, 200, GG);
    if (j >= 1)
      proj_gemm<<<pgrid, pblk, 0, stream>>>(
          seqA, (long long)CH * HH, HH, 0, 0,
          dWih1, dbih1, dbhh1,
          xpB, (long long)CH * GG, GG, 0, CH, HH, GG);
    lstm_rec_mfma2<<<rgrid, rblk, 0, stream>>>(
        (j < nchunks) ? xpA : (const float*)nullptr, dW0hi, dW0lo,
        h0s, c0s, seqA, 0,
        (j >= 1) ? xpB : (const float*)nullptr, dW1hi, dW1lo,
        h1s, c1s, seqB, 0,
        CH);
    if (j >= 1)
      proj_gemm<<<fgrid, pblk, 0, stream>>>(
          seqB, (long long)CH * HH, HH, 0, 0,
          fcW, fcb, (const float*)nullptr,
          out, (long long)S * 200, 200, (j - 1) * CH, CH, HH, 200);
  }
}